// Round 6
// baseline (779.099 us; speedup 1.0000x reference)
//
#include <hip/hip_runtime.h>
#include <stdint.h>

// out[t,b,c,h,w] = (t >= 64*x) * (threefry_xor_bits(rkey, j) <= 0xC00001FF)
// out shape (64,16,3,224,224) fp32; N = 154,140,672 < 2^32.
// PRNG (verified bit-exact R3/R4/R5, absmax=0): JAX partitionable 32-bit
// random_bits: bits[j] = o0 ^ o1 of threefry2x32(rkey, (0, j)).
static constexpr uint32_t M = 16u * 3u * 224u * 224u;  // 2,408,448 per timestep

// uniform <= 0.75  <=>  bits <= 0xC00001FF
static constexpr uint32_t BITS_LE = 0xC00001FFu;

// Host-precomputed key schedule (round-1 fold + injection folding, R5-proven).
struct Keys {
  uint32_t k1, k01;
  uint32_t AB1, B1, AB2, B2, AB3, B3, AB4, B4, A5, B5;
};

__device__ __forceinline__ uint32_t rotl(uint32_t v, int n) {
  return __builtin_rotateleft32(v, n);  // v_alignbit_b32
}

// grid = (M/8/256, 8) = (1176, 8). Each thread: 8 consecutive sites x 8
// timesteps = 64 elements. Inner loop: 4 iterations x 2 timesteps with 16
// interleaved threefry chains; 4 float4 stores at iteration end (register
// reuse ~2200 VALU-cycles later -> no vmcnt stall, unlike R4's VGPR=28 loop).
__global__ __launch_bounds__(256) void spike_encode(const float* __restrict__ x,
                                                    float* __restrict__ out,
                                                    Keys K) {
  const uint32_t m8 = (blockIdx.x * 256u + threadIdx.x) * 8u;
  const uint32_t t0 = blockIdx.y * 8u;

  const float4 xa = *reinterpret_cast<const float4*>(x + m8);
  const float4 xb = *reinterpret_cast<const float4*>(x + m8 + 4u);
  // (t - 64x >= 0) <=> (t >= 64x) in fp32 (verified, absmax=0).
  const float d[8] = {xa.x * 64.0f, xa.y * 64.0f, xa.z * 64.0f, xa.w * 64.0f,
                      xb.x * 64.0f, xb.y * 64.0f, xb.z * 64.0f, xb.w * 64.0f};

  uint32_t ja = t0 * M + m8;     // flat index of (t, m8); max < 2^32
  float tfa = (float)t0;
  float tfb = tfa + 1.0f;

#pragma unroll 1
  for (int it = 0; it < 4; ++it) {
    const uint32_t jb = ja + M;  // (t+1, m8)

    uint32_t x0[16], x1[16];
#pragma unroll
    for (int i = 0; i < 16; ++i) {
      const uint32_t jj = (i < 8 ? ja : jb) + (uint32_t)(i & 7);
      x1[i] = jj + K.k1;
      x0[i] = jj + K.k01;  // round-1 "x0 += x1" pre-folded
    }

#define RND(r) \
  _Pragma("unroll") for (int i = 0; i < 16; ++i) { \
    x0[i] += x1[i]; x1[i] = rotl(x1[i], r) ^ x0[i]; \
  }
#define INJR(AB, B, r) \
  _Pragma("unroll") for (int i = 0; i < 16; ++i) { \
    x0[i] = x0[i] + x1[i] + K.AB; \
    x1[i] = rotl(x1[i] + K.B, r) ^ x0[i]; \
  }
    // round 1 (reduced), rounds 2-20 with folded injections:
#pragma unroll
    for (int i = 0; i < 16; ++i) x1[i] = rotl(x1[i], 13) ^ x0[i];
    RND(15) RND(26) RND(6)
    INJR(AB1, B1, 17)
    RND(29) RND(16) RND(24)
    INJR(AB2, B2, 13)
    RND(15) RND(26) RND(6)
    INJR(AB3, B3, 17)
    RND(29) RND(16) RND(24)
    INJR(AB4, B4, 13)
    RND(15) RND(26) RND(6)
#undef RND
#undef INJR

    float o[16];
#pragma unroll
    for (int i = 0; i < 16; ++i) {
      const uint32_t b = (x0[i] + K.A5) ^ (x1[i] + K.B5);  // terminal injection
      const float tf = (i < 8) ? tfa : tfb;
      o[i] = ((tf >= d[i & 7]) && (b <= BITS_LE)) ? 1.0f : 0.0f;
    }

    const float4 s0 = {o[0],  o[1],  o[2],  o[3]};
    const float4 s1 = {o[4],  o[5],  o[6],  o[7]};
    const float4 s2 = {o[8],  o[9],  o[10], o[11]};
    const float4 s3 = {o[12], o[13], o[14], o[15]};
    *reinterpret_cast<float4*>(out + (size_t)ja)      = s0;
    *reinterpret_cast<float4*>(out + (size_t)ja + 4u) = s1;
    *reinterpret_cast<float4*>(out + (size_t)jb)      = s2;
    *reinterpret_cast<float4*>(out + (size_t)jb + 4u) = s3;

    ja  += 2u * M;
    tfa += 2.0f;
    tfb += 2.0f;
  }
}

// Host-side full threefry2x32 for key derivation.
static inline void tf2x32_host(uint32_t k0, uint32_t k1, uint32_t& x0, uint32_t& x1) {
  const uint32_t ks2 = k0 ^ k1 ^ 0x1BD11BDAu;
  x0 += k0; x1 += k1;
  auto rnd = [&](int r) { x0 += x1; x1 = (x1 << r) | (x1 >> (32 - r)); x1 ^= x0; };
  rnd(13); rnd(15); rnd(26); rnd(6);  x0 += k1;  x1 += ks2 + 1u;
  rnd(17); rnd(29); rnd(16); rnd(24); x0 += ks2; x1 += k0 + 2u;
  rnd(13); rnd(15); rnd(26); rnd(6);  x0 += k0;  x1 += k1 + 3u;
  rnd(17); rnd(29); rnd(16); rnd(24); x0 += k1;  x1 += ks2 + 4u;
  rnd(13); rnd(15); rnd(26); rnd(6);  x0 += ks2; x1 += k0 + 5u;
}

extern "C" void kernel_launch(void* const* d_in, const int* in_sizes, int n_in,
                              void* d_out, int out_size, void* d_ws, size_t ws_size,
                              hipStream_t stream) {
  (void)in_sizes; (void)n_in; (void)out_size; (void)d_ws; (void)ws_size;
  const float* x = (const float*)d_in[0];
  float* out = (float*)d_out;

  // rkey = fold_in(key(0), 1) = threefry2x32(key=(0,0), counts=(0,1))
  uint32_t rk0 = 0u, rk1 = 1u;
  tf2x32_host(0u, 0u, rk0, rk1);

  const uint32_t ks2 = rk0 ^ rk1 ^ 0x1BD11BDAu;
  Keys K;
  K.k1  = rk1;
  K.k01 = rk0 + rk1;
  const uint32_t A1 = rk1, B1 = ks2 + 1u;
  const uint32_t A2 = ks2, B2 = rk0 + 2u;
  const uint32_t A3 = rk0, B3 = rk1 + 3u;
  const uint32_t A4 = rk1, B4 = ks2 + 4u;
  K.AB1 = A1 + B1; K.B1 = B1;
  K.AB2 = A2 + B2; K.B2 = B2;
  K.AB3 = A3 + B3; K.B3 = B3;
  K.AB4 = A4 + B4; K.B4 = B4;
  K.A5  = ks2;     K.B5 = rk0 + 5u;

  dim3 grid(M / 8u / 256u, 8);  // (1176, 8): 8 sites x 8 timesteps per thread
  spike_encode<<<grid, dim3(256), 0, stream>>>(x, out, K);
}

// Round 7
// 767.899 us; speedup vs baseline: 1.0146x; 1.0146x over previous
//
#include <hip/hip_runtime.h>
#include <stdint.h>

// out[t,b,c,h,w] = (t >= 64*x) * (threefry_xor_bits(rkey, j) <= 0xC00001FF)
// out shape (64,16,3,224,224) fp32; N = 154,140,672 < 2^32.
// PRNG (verified bit-exact R3-R6, absmax=0): JAX partitionable 32-bit
// random_bits: bits[j] = o0 ^ o1 of threefry2x32(rkey, (0, j)).
//
// Perf history: R3 flat/4-chain 364us; R4 t-loop 418us (VGPR=28 store stall);
// R5 flat/8-chain 375us; R6 8x-work t-loop 382us. Structure-insensitive
// => issue/clock-bound. This round: R3 topology + injection folding (-5% ops).
static constexpr uint32_t M = 16u * 3u * 224u * 224u;  // 2,408,448 per timestep

// uniform <= 0.75  <=>  bits <= 0xC00001FF
static constexpr uint32_t BITS_LE = 0xC00001FFu;

// Host-precomputed key schedule. counts=(0,j): x0_in=rk0, x1_in=j+rk1.
// Round-1 "x0 += x1" folded into init (x0 = j + k01).
// Injection i folded into the next round's add via v_add3_u32.
struct Keys {
  uint32_t k1, k01;
  uint32_t AB1, B1, AB2, B2, AB3, B3, AB4, B4, A5, B5;
};

__device__ __forceinline__ uint32_t rotl(uint32_t v, int n) {
  return __builtin_rotateleft32(v, n);  // v_alignbit_b32
}

// grid = (M/4/256, 64) = (2352, 64); blockIdx.y = timestep t. Flat: one t per
// thread, 4 consecutive sites = 4 independent threefry chains, one float4
// store at thread end (fire-and-forget). Fastest known topology (R3).
__global__ __launch_bounds__(256) void spike_encode(const float* __restrict__ x,
                                                    float* __restrict__ out,
                                                    Keys K) {
  const uint32_t m4 = (blockIdx.x * 256u + threadIdx.x) * 4u;
  const uint32_t t  = blockIdx.y;
  const float tf = (float)t;
  const uint32_t j = t * M + m4;

  const float4 xv = *reinterpret_cast<const float4*>(x + m4);
  // (t - 64x >= 0) <=> (t >= 64x) in fp32 (verified, absmax=0).
  const float d[4] = {xv.x * 64.0f, xv.y * 64.0f, xv.z * 64.0f, xv.w * 64.0f};

  uint32_t x0[4], x1[4];
#pragma unroll
  for (int i = 0; i < 4; ++i) {
    x1[i] = j + (K.k1  + (uint32_t)i);
    x0[i] = j + (K.k01 + (uint32_t)i);  // round-1 "x0 += x1" pre-folded
  }

#define RND(r) \
  _Pragma("unroll") for (int i = 0; i < 4; ++i) { \
    x0[i] += x1[i]; x1[i] = rotl(x1[i], r) ^ x0[i]; \
  }
// Injection folded into following round (rotation r):
//   x0 = x0 + x1 + (A+B)  [v_add3_u32];  x1 = rotl(x1 + B, r) ^ x0
#define INJR(AB, B, r) \
  _Pragma("unroll") for (int i = 0; i < 4; ++i) { \
    x0[i] = x0[i] + x1[i] + K.AB; \
    x1[i] = rotl(x1[i] + K.B, r) ^ x0[i]; \
  }

  // round 1 (reduced), rounds 2-20 with folded injections:
#pragma unroll
  for (int i = 0; i < 4; ++i) x1[i] = rotl(x1[i], 13) ^ x0[i];
  RND(15) RND(26) RND(6)
  INJR(AB1, B1, 17)           // inj1 + round 5
  RND(29) RND(16) RND(24)
  INJR(AB2, B2, 13)           // inj2 + round 9
  RND(15) RND(26) RND(6)
  INJR(AB3, B3, 17)           // inj3 + round 13
  RND(29) RND(16) RND(24)
  INJR(AB4, B4, 13)           // inj4 + round 17
  RND(15) RND(26) RND(6)      // rounds 18-20
#undef RND
#undef INJR

  float o[4];
#pragma unroll
  for (int i = 0; i < 4; ++i) {
    const uint32_t b = (x0[i] + K.A5) ^ (x1[i] + K.B5);  // terminal injection
    o[i] = ((tf >= d[i]) && (b <= BITS_LE)) ? 1.0f : 0.0f;
  }

  const float4 s = {o[0], o[1], o[2], o[3]};
  *reinterpret_cast<float4*>(out + (size_t)j) = s;
}

// Host-side full threefry2x32 for key derivation.
static inline void tf2x32_host(uint32_t k0, uint32_t k1, uint32_t& x0, uint32_t& x1) {
  const uint32_t ks2 = k0 ^ k1 ^ 0x1BD11BDAu;
  x0 += k0; x1 += k1;
  auto rnd = [&](int r) { x0 += x1; x1 = (x1 << r) | (x1 >> (32 - r)); x1 ^= x0; };
  rnd(13); rnd(15); rnd(26); rnd(6);  x0 += k1;  x1 += ks2 + 1u;
  rnd(17); rnd(29); rnd(16); rnd(24); x0 += ks2; x1 += k0 + 2u;
  rnd(13); rnd(15); rnd(26); rnd(6);  x0 += k0;  x1 += k1 + 3u;
  rnd(17); rnd(29); rnd(16); rnd(24); x0 += k1;  x1 += ks2 + 4u;
  rnd(13); rnd(15); rnd(26); rnd(6);  x0 += ks2; x1 += k0 + 5u;
}

extern "C" void kernel_launch(void* const* d_in, const int* in_sizes, int n_in,
                              void* d_out, int out_size, void* d_ws, size_t ws_size,
                              hipStream_t stream) {
  (void)in_sizes; (void)n_in; (void)out_size; (void)d_ws; (void)ws_size;
  const float* x = (const float*)d_in[0];
  float* out = (float*)d_out;

  // rkey = fold_in(key(0), 1) = threefry2x32(key=(0,0), counts=(0,1))
  uint32_t rk0 = 0u, rk1 = 1u;
  tf2x32_host(0u, 0u, rk0, rk1);

  const uint32_t ks2 = rk0 ^ rk1 ^ 0x1BD11BDAu;
  Keys K;
  K.k1  = rk1;
  K.k01 = rk0 + rk1;
  const uint32_t A1 = rk1, B1 = ks2 + 1u;
  const uint32_t A2 = ks2, B2 = rk0 + 2u;
  const uint32_t A3 = rk0, B3 = rk1 + 3u;
  const uint32_t A4 = rk1, B4 = ks2 + 4u;
  K.AB1 = A1 + B1; K.B1 = B1;
  K.AB2 = A2 + B2; K.B2 = B2;
  K.AB3 = A3 + B3; K.B3 = B3;
  K.AB4 = A4 + B4; K.B4 = B4;
  K.A5  = ks2;     K.B5 = rk0 + 5u;

  dim3 grid(M / 4u / 256u, 64);  // (2352, 64): R3's fastest topology
  spike_encode<<<grid, dim3(256), 0, stream>>>(x, out, K);
}